// Round 11
// baseline (1835.707 us; speedup 1.0000x reference)
//
#include <hip/hip_runtime.h>
#include <math.h>

#define Bsz 32
#define Lseq 1024
#define CHUNK 64
#define NCHUNK 16

__device__ __forceinline__ float fsig(float x) {
    return __builtin_amdgcn_rcpf(1.f + __expf(-x));
}
// Accurate fast tanh: Taylor for small |x| (avoids catastrophic cancellation
// in the exp form at x~1e-7, which killed R2), exp form for large |x|.
__device__ __forceinline__ float ftanh(float x) {
    float x2 = x * x;
    float poly = x * (1.f - 0.333333333f * x2 + 0.133333333f * x2 * x2);
    float big = 1.f - 2.f * __builtin_amdgcn_rcpf(1.f + __expf(2.f * x));
    return (x2 < 0.0025f) ? poly : big;
}
__device__ __forceinline__ float fsilu(float x) {
    return x * __builtin_amdgcn_rcpf(1.f + __expf(-x));
}

// ---------------- precompute: folded weight products ----------------
__global__ void k_pre(const float* w_proj, const float* b_proj, const float* w_inproj,
                      const float* A_log, const float* w_ih, const float* w_out,
                      const float* b_ih, const float* b_hh,
                      float* Ab, float* Minp, float* cinp, float* M2T, float* c2) {
    int idx = blockIdx.x * 256 + threadIdx.x;
    if (idx < 4096) {
        Ab[idx] = -expf(A_log[idx]);
    } else if (idx < 4096 + 6144) {
        int j = idx - 4096; int o = j / 12; int i = j - o * 12;
        float s = 0.f;
        for (int k = 0; k < 128; ++k) s += w_inproj[o*128+k] * w_proj[k*12+i];
        Minp[j] = s;
    } else if (idx < 4096 + 6144 + 512) {
        int o = idx - (4096 + 6144);
        float s = 0.f;
        for (int k = 0; k < 128; ++k) s += w_inproj[o*128+k] * b_proj[k];
        cinp[o] = s;
    } else if (idx < 4096 + 6144 + 512 + 131072) {
        int j = idx - (4096 + 6144 + 512);
        int o = j >> 8; int dd = j & 255;
        float s = 0.f;
        for (int k = 0; k < 128; ++k) s += w_ih[o*128+k] * w_out[k*256+dd];
        M2T[dd*512 + o] = s;    // transposed store
    } else if (idx < 4096 + 6144 + 512 + 131072 + 512) {
        int o = idx - (4096 + 6144 + 512 + 131072);
        c2[o] = b_ih[o] + b_hh[o];
    }
}

// ---------------- k_front: fused inproj + depthwise conv + SiLU ----------------
__global__ void __launch_bounds__(256) k_front(const float* __restrict__ x,
                       const float* __restrict__ Minp, const float* __restrict__ cinp,
                       const float* __restrict__ conv_w, const float* __restrict__ conv_b,
                       float* __restrict__ uc, float* __restrict__ zb) {
    __shared__ float xs[67*12];
    int b = blockIdx.x >> 4;
    int c = blockIdx.x & 15;
    int d = threadIdx.x;
    int t0 = c * 64;
    for (int i = d; i < 67*12; i += 256) {
        int trel = i / 12;
        int t = t0 - 3 + trel;
        xs[i] = (t >= 0) ? x[(b*1024 + t)*12 + (i - trel*12)] : 0.f;
    }
    __syncthreads();
    float mu[12], mz[12];
#pragma unroll
    for (int i = 0; i < 12; ++i) { mu[i] = Minp[d*12 + i]; mz[i] = Minp[(256+d)*12 + i]; }
    float cu = cinp[d], cz = cinp[256 + d];
    float cw0 = conv_w[d*4+0], cw1 = conv_w[d*4+1], cw2 = conv_w[d*4+2], cw3 = conv_w[d*4+3];
    float cb = conv_b[d];
    float r0 = 0.f, r1 = 0.f, r2 = 0.f;
#pragma unroll
    for (int k = 0; k < 3; ++k) {
        int t = t0 - 3 + k;
        float v = 0.f;
        if (t >= 0) {
            const float* xr = &xs[k*12];
            v = cu;
#pragma unroll
            for (int i = 0; i < 12; ++i) v += mu[i]*xr[i];
        }
        r0 = r1; r1 = r2; r2 = v;
    }
    for (int t = t0; t < t0 + 64; ++t) {
        const float* xr = &xs[(t - t0 + 3)*12];
        float u = cu, z = cz;
#pragma unroll
        for (int i = 0; i < 12; ++i) { u += mu[i]*xr[i]; z += mz[i]*xr[i]; }
        float cv = cb + cw0*r0 + cw1*r1 + cw2*r2 + cw3*u;
        uc[(b*1024 + t)*256 + d] = fsilu(cv);
        zb[(b*1024 + t)*256 + d] = z;
        r0 = r1; r1 = r2; r2 = u;
    }
}

// ---------------- k3: xdbc = uc @ w_xproj^T; dt = softplus(...) ----------------
__global__ void __launch_bounds__(256) k_xproj(const float* __restrict__ uc,
                        const float* __restrict__ w_xproj, const float* __restrict__ w_dt,
                        const float* __restrict__ b_dt,
                        float* __restrict__ dtb, float* __restrict__ Bm, float* __restrict__ Cm) {
    __shared__ float ur[256];
    __shared__ float xd[40];
    int tok = blockIdx.x;
    int tid = threadIdx.x;
    ur[tid] = uc[tok*256 + tid];
    __syncthreads();
    int j = tid >> 2, q = tid & 3;
    float s = 0.f;
    if (j < 40) {
        const float* wr = w_xproj + j*256 + q*64;
        const float* uq = ur + q*64;
#pragma unroll 8
        for (int k = 0; k < 64; ++k) s += wr[k] * uq[k];
    }
    s += __shfl_xor(s, 1);
    s += __shfl_xor(s, 2);
    if (j < 40 && q == 0) {
        xd[j] = s;
        if (j >= 8 && j < 24)      Bm[tok*16 + (j - 8)]  = s;
        else if (j >= 24)          Cm[tok*16 + (j - 24)] = s;
    }
    __syncthreads();
    float r = b_dt[tid];
    const float* wd = w_dt + tid*8;
#pragma unroll
    for (int jj = 0; jj < 8; ++jj) r += wd[jj] * xd[jj];
    r = (r > 20.f) ? r : log1pf(expf(r));   // softplus
    dtb[tok*256 + tid] = r;
}

// ---------------- SSM chunked scan ----------------
__global__ void __launch_bounds__(256) k_ssm_p1(const float* __restrict__ dtb,
                        const float* __restrict__ uc, const float* __restrict__ Bm,
                        const float* __restrict__ Ab,
                        float* __restrict__ h0end, float* __restrict__ Ssum) {
    __shared__ float Bs[CHUNK*16];
    int b = blockIdx.x >> 4;
    int c = blockIdx.x & 15;
    int d = threadIdx.x;
    int t0 = c * CHUNK;
    {
        const float* src = Bm + (b*1024 + t0) * 16;
        for (int i = d; i < CHUNK*16; i += 256) Bs[i] = src[i];
    }
    __syncthreads();
    float a[16], h[16];
#pragma unroll
    for (int s = 0; s < 16; ++s) { a[s] = Ab[d*16+s]; h[s] = 0.f; }
    float S = 0.f;
    const float* dtp = dtb + (b*1024 + t0)*256 + d;
    const float* up  = uc  + (b*1024 + t0)*256 + d;
    float dtv = dtp[0], uv = up[0];
    for (int t = 0; t < CHUNK; ++t) {
        float dtn = 0.f, un = 0.f;
        if (t < CHUNK-1) { dtn = dtp[(t+1)*256]; un = up[(t+1)*256]; }
        float dtu = dtv * uv;
        S += dtv;
#pragma unroll
        for (int s = 0; s < 16; ++s) {
            float dA = __expf(dtv * a[s]);
            h[s] = h[s]*dA + dtu * Bs[t*16+s];
        }
        dtv = dtn; uv = un;
    }
    float* he = h0end + ((b*256 + d)*16 + c)*16;
#pragma unroll
    for (int s = 0; s < 16; ++s) he[s] = h[s];
    Ssum[(b*256 + d)*16 + c] = S;
}

__global__ void k_ssm_p2(const float* __restrict__ h0end, const float* __restrict__ Ssum,
                         const float* __restrict__ Ab, float* __restrict__ hinit) {
    int gid = blockIdx.x * 256 + threadIdx.x;   // 131072 = 32*256*16
    int s = gid & 15;
    int bd = gid >> 4;
    int d = bd & 255;
    float a = Ab[d*16 + s];
    float carry = 0.f;
    const float* he = h0end + bd * 256;
    float* hi = hinit + bd * 256;
    const float* Sp = Ssum + bd * 16;
    for (int c = 0; c < 16; ++c) {
        hi[c*16 + s] = carry;
        carry = he[c*16 + s] + __expf(a * Sp[c]) * carry;
    }
}

__global__ void __launch_bounds__(256) k_ssm_p3(const float* __restrict__ dtb,
                        const float* __restrict__ uc, const float* __restrict__ zb,
                        const float* __restrict__ Bm, const float* __restrict__ Cm,
                        const float* __restrict__ Ab, const float* __restrict__ Dskip,
                        const float* __restrict__ hinit, float* __restrict__ yg) {
    __shared__ float Bs[CHUNK*16];
    __shared__ float Cs[CHUNK*16];
    int b = blockIdx.x >> 4;
    int c = blockIdx.x & 15;
    int d = threadIdx.x;
    int t0 = c * CHUNK;
    {
        const float* srcB = Bm + (b*1024 + t0) * 16;
        const float* srcC = Cm + (b*1024 + t0) * 16;
        for (int i = d; i < CHUNK*16; i += 256) { Bs[i] = srcB[i]; Cs[i] = srcC[i]; }
    }
    __syncthreads();
    float a[16], h[16];
    const float* hi = hinit + ((b*256 + d)*16 + c)*16;
#pragma unroll
    for (int s = 0; s < 16; ++s) { a[s] = Ab[d*16+s]; h[s] = hi[s]; }
    float Dv = Dskip[d];
    const float* dtp = dtb + (b*1024 + t0)*256 + d;
    const float* up  = uc  + (b*1024 + t0)*256 + d;
    const float* zp  = zb  + (b*1024 + t0)*256 + d;
    float* yp = yg + (b*1024 + t0)*256 + d;
    float dtv = dtp[0], uv = up[0], zv = zp[0];
    for (int t = 0; t < CHUNK; ++t) {
        float dtn = 0.f, un = 0.f, zn = 0.f;
        if (t < CHUNK-1) { dtn = dtp[(t+1)*256]; un = up[(t+1)*256]; zn = zp[(t+1)*256]; }
        float dtu = dtv * uv;
        float y = 0.f;
#pragma unroll
        for (int s = 0; s < 16; ++s) {
            float dA = __expf(dtv * a[s]);
            h[s] = h[s]*dA + dtu * Bs[t*16+s];
            y += h[s] * Cs[t*16+s];
        }
        yp[t*256] = (y + uv * Dv) * fsilu(zv);
        dtv = dtn; uv = un; zv = zn;
    }
}

// ---------------- k5: xg = yg @ M2^T + c2  via transposed M2T, coalesced ----
__global__ void __launch_bounds__(256) k_xg(const float* __restrict__ yg,
                      const float* __restrict__ M2T, const float* __restrict__ c2,
                      float* __restrict__ xg) {
    __shared__ float ytile[16][257];
    int tokbase = blockIdx.x * 16;
    int tid = threadIdx.x;
    for (int r = 0; r < 16; ++r) ytile[r][tid] = yg[(tokbase + r)*256 + tid];
    __syncthreads();
    int o0 = tid, o1 = tid + 256;
    float acc0[16], acc1[16];
    float cc0 = c2[o0], cc1 = c2[o1];
#pragma unroll
    for (int r = 0; r < 16; ++r) { acc0[r] = cc0; acc1[r] = cc1; }
#pragma unroll 4
    for (int k = 0; k < 256; ++k) {
        float m0 = M2T[k*512 + o0];
        float m1 = M2T[k*512 + o1];
#pragma unroll
        for (int r = 0; r < 16; ++r) {
            float yv = ytile[r][k];
            acc0[r] = fmaf(yv, m0, acc0[r]);
            acc1[r] = fmaf(yv, m1, acc1[r]);
        }
    }
    for (int r = 0; r < 16; ++r) {
        xg[(tokbase + r)*512 + o0] = acc0[r];
        xg[(tokbase + r)*512 + o1] = acc1[r];
    }
}

// ---------------- k6: LSTM (one block per batch) + FC head ----------------
// Measured invariant decoded: R4's 3100 cyc/step == 8 waves x 32 b128
// h-broadcasts x 12 cyc (LDS delivers ~85 B/cyc TO LANES; broadcast costs the
// same as a full read). R10's readlane path hit a separate VALU-hazard wall.
// Fix: halve the h bytes -- h lives in LDS as 64 u32 of PACKED bf16 PAIRS.
// 16 b128 broadcasts/thread/step (768 B/lane -> 256 B/lane h traffic).
// Unpack is exact+cheap: (u<<16) and (u&0xffff0000) ARE the f32 bit patterns
// of the two bf16 halves. Weights stay fp32: R9's proven 64-VGPR(named
// float4) + 64-AGPR residency (VGPR 96). cstate stays fp32; h is re-derived
// from fp32 cstate each step so bf16-h error (~0.2% rel, RNE) does not
// self-amplify; final h kept fp32 in hf[] for the FC head.
#define UNLO(u) __uint_as_float((u) << 16)
#define UNHI(u) __uint_as_float((u) & 0xffff0000u)
#define LW(i) float4 W##i = wr[i];
// h4[i] covers k=8i..8i+7; weight quads WA=W(2i) k=8i..8i+3, WB=W(2i+1)
#define DOTP_V(i, WA, WB) { uint4 hu = h4[i]; \
    a0 = fmaf(UNLO(hu.x), WA.x, a0); a1 = fmaf(UNHI(hu.x), WA.y, a1); \
    a2 = fmaf(UNLO(hu.y), WA.z, a2); a3 = fmaf(UNHI(hu.y), WA.w, a3); \
    a0 = fmaf(UNLO(hu.z), WB.x, a0); a1 = fmaf(UNHI(hu.z), WB.y, a1); \
    a2 = fmaf(UNLO(hu.w), WB.z, a2); a3 = fmaf(UNHI(hu.w), WB.w, a3); }
#define WADECL(i) float wa_##i##_0, wa_##i##_1, wa_##i##_2, wa_##i##_3;
#define WALOAD(i) { float4 v = wr[i]; \
    asm volatile("v_accvgpr_write_b32 %0, %1" : "=a"(wa_##i##_0) : "v"(v.x)); \
    asm volatile("v_accvgpr_write_b32 %0, %1" : "=a"(wa_##i##_1) : "v"(v.y)); \
    asm volatile("v_accvgpr_write_b32 %0, %1" : "=a"(wa_##i##_2) : "v"(v.z)); \
    asm volatile("v_accvgpr_write_b32 %0, %1" : "=a"(wa_##i##_3) : "v"(v.w)); }
#define DOTP_A(i, qa, qb) { uint4 hu = h4[i]; float t0,t1,t2,t3,t4,t5,t6,t7; \
    asm volatile("v_accvgpr_read_b32 %0, %1" : "=v"(t0) : "a"(wa_##qa##_0)); \
    asm volatile("v_accvgpr_read_b32 %0, %1" : "=v"(t1) : "a"(wa_##qa##_1)); \
    asm volatile("v_accvgpr_read_b32 %0, %1" : "=v"(t2) : "a"(wa_##qa##_2)); \
    asm volatile("v_accvgpr_read_b32 %0, %1" : "=v"(t3) : "a"(wa_##qa##_3)); \
    asm volatile("v_accvgpr_read_b32 %0, %1" : "=v"(t4) : "a"(wa_##qb##_0)); \
    asm volatile("v_accvgpr_read_b32 %0, %1" : "=v"(t5) : "a"(wa_##qb##_1)); \
    asm volatile("v_accvgpr_read_b32 %0, %1" : "=v"(t6) : "a"(wa_##qb##_2)); \
    asm volatile("v_accvgpr_read_b32 %0, %1" : "=v"(t7) : "a"(wa_##qb##_3)); \
    a0 = fmaf(UNLO(hu.x), t0, a0); a1 = fmaf(UNHI(hu.x), t1, a1); \
    a2 = fmaf(UNLO(hu.y), t2, a2); a3 = fmaf(UNHI(hu.y), t3, a3); \
    a0 = fmaf(UNLO(hu.z), t4, a0); a1 = fmaf(UNHI(hu.z), t5, a1); \
    a2 = fmaf(UNLO(hu.w), t6, a2); a3 = fmaf(UNHI(hu.w), t7, a3); }

__global__ void __launch_bounds__(512)
k_lstm(const float* __restrict__ xg,
                       const float* __restrict__ w_hh,
                       const float* __restrict__ w_fc1, const float* __restrict__ b_fc1,
                       const float* __restrict__ w_fc2, const float* __restrict__ b_fc2,
                       float* __restrict__ out) {
    __shared__ unsigned hb2[64];       // 128 h values as packed bf16 pairs
    __shared__ float gbuf[512];
    __shared__ float hf[128];          // final-step h in fp32 for FC head
    int b = blockIdx.x;
    int tid = threadIdx.x;   // gate output index o
    const float4* wr = (const float4*)(w_hh + tid*128);
    // k = 0..63 in named VGPR float4s
    LW(0)  LW(1)  LW(2)  LW(3)  LW(4)  LW(5)  LW(6)  LW(7)
    LW(8)  LW(9)  LW(10) LW(11) LW(12) LW(13) LW(14) LW(15)
    // k = 64..127 in AGPRs
    WADECL(16) WADECL(17) WADECL(18) WADECL(19)
    WADECL(20) WADECL(21) WADECL(22) WADECL(23)
    WADECL(24) WADECL(25) WADECL(26) WADECL(27)
    WADECL(28) WADECL(29) WADECL(30) WADECL(31)
    WALOAD(16) WALOAD(17) WALOAD(18) WALOAD(19)
    WALOAD(20) WALOAD(21) WALOAD(22) WALOAD(23)
    WALOAD(24) WALOAD(25) WALOAD(26) WALOAD(27)
    WALOAD(28) WALOAD(29) WALOAD(30) WALOAD(31)
    float cstate = 0.f;
    if (tid < 64) hb2[tid] = 0u;
    __syncthreads();
    const float* xgb = xg + (size_t)b * 1024 * 512;
    float gx = xgb[tid];
    const uint4* h4 = (const uint4*)hb2;
    for (int t = 0; t < 1024; ++t) {
        float gxn = (t < 1023) ? xgb[(t+1)*512 + tid] : 0.f;   // prefetch
        float a0 = 0.f, a1 = 0.f, a2 = 0.f, a3 = 0.f;
        DOTP_V(0, W0,  W1)  DOTP_V(1, W2,  W3)
        DOTP_V(2, W4,  W5)  DOTP_V(3, W6,  W7)
        DOTP_V(4, W8,  W9)  DOTP_V(5, W10, W11)
        DOTP_V(6, W12, W13) DOTP_V(7, W14, W15)
        DOTP_A(8,  16, 17)  DOTP_A(9,  18, 19)
        DOTP_A(10, 20, 21)  DOTP_A(11, 22, 23)
        DOTP_A(12, 24, 25)  DOTP_A(13, 26, 27)
        DOTP_A(14, 28, 29)  DOTP_A(15, 30, 31)
        gbuf[tid] = gx + ((a0 + a1) + (a2 + a3));
        __syncthreads();
        if (tid < 128) {
            float ig = fsig(gbuf[tid]);
            float fg = fsig(gbuf[tid+128]);
            float gg = ftanh(gbuf[tid+256]);
            float og = fsig(gbuf[tid+384]);
            cstate = fg*cstate + ig*gg;
            float h = og * ftanh(cstate);
            // RNE bf16 pack; pair (even j -> lo, odd j -> hi)
            unsigned u = __float_as_uint(h);
            unsigned r = (u + 0x7fffu + ((u >> 16) & 1u)) >> 16;
            unsigned o2 = (unsigned)__shfl_xor((int)r, 1);
            if (!(tid & 1)) hb2[tid >> 1] = (o2 << 16) | r;
            if (t == 1023) hf[tid] = h;
        }
        __syncthreads();
        gx = gxn;
    }
    // FC head
    if (tid < 128) {
        float s = b_fc1[tid];
        const float* wf = w_fc1 + tid*128;
#pragma unroll 4
        for (int k = 0; k < 128; ++k) s += wf[k] * hf[k];
        gbuf[tid] = fmaxf(s, 0.f);
    }
    __syncthreads();
    if (tid < 5) {
        float s = b_fc2[tid];
        const float* wf = w_fc2 + tid*128;
        for (int k = 0; k < 128; ++k) s += wf[k] * gbuf[k];
        out[b*5 + tid] = s;
    }
}

// ---------------- launch ----------------
extern "C" void kernel_launch(void* const* d_in, const int* in_sizes, int n_in,
                              void* d_out, int out_size, void* d_ws, size_t ws_size,
                              hipStream_t stream) {
    const float* x        = (const float*)d_in[0];
    const float* w_proj   = (const float*)d_in[1];
    const float* b_proj   = (const float*)d_in[2];
    const float* w_inproj = (const float*)d_in[3];
    const float* conv_w   = (const float*)d_in[4];
    const float* conv_b   = (const float*)d_in[5];
    const float* w_xproj  = (const float*)d_in[6];
    const float* w_dt     = (const float*)d_in[7];
    const float* b_dt     = (const float*)d_in[8];
    const float* A_log    = (const float*)d_in[9];
    const float* Dskip    = (const float*)d_in[10];
    const float* w_out    = (const float*)d_in[11];
    const float* w_ih     = (const float*)d_in[12];
    const float* w_hh     = (const float*)d_in[13];
    const float* b_ih     = (const float*)d_in[14];
    const float* b_hh     = (const float*)d_in[15];
    const float* w_fc1    = (const float*)d_in[16];
    const float* b_fc1    = (const float*)d_in[17];
    const float* w_fc2    = (const float*)d_in[18];
    const float* b_fc2    = (const float*)d_in[19];
    float* outp = (float*)d_out;

    float* ws = (float*)d_ws;
    size_t off = 0;
    float* uc   = ws + off; off += 8388608;   // xg aliases uc+zb after p3
    float* zb   = ws + off; off += 8388608;
    float* dtb  = ws + off; off += 8388608;
    float* yg   = ws + off; off += 8388608;
    float* Bm   = ws + off; off += 524288;
    float* Cm   = ws + off; off += 524288;
    float* Ab   = ws + off; off += 4096;
    float* Minp = ws + off; off += 6144;
    float* cinp = ws + off; off += 512;
    float* M2T  = ws + off; off += 131072;
    float* c2   = ws + off; off += 512;
    float* h0end = ws + off; off += 2097152;
    float* Ssum  = ws + off; off += 131072;
    float* hinit = ws + off; off += 2097152;
    float* xg = uc;    // alias: spans uc+zb (16.7M floats), both dead after ssm_p3

    k_pre<<<556, 256, 0, stream>>>(w_proj, b_proj, w_inproj, A_log, w_ih, w_out,
                                   b_ih, b_hh, Ab, Minp, cinp, M2T, c2);
    k_front<<<512, 256, 0, stream>>>(x, Minp, cinp, conv_w, conv_b, uc, zb);
    k_xproj<<<32768, 256, 0, stream>>>(uc, w_xproj, w_dt, b_dt, dtb, Bm, Cm);
    k_ssm_p1<<<512, 256, 0, stream>>>(dtb, uc, Bm, Ab, h0end, Ssum);
    k_ssm_p2<<<512, 256, 0, stream>>>(h0end, Ssum, Ab, hinit);
    k_ssm_p3<<<512, 256, 0, stream>>>(dtb, uc, zb, Bm, Cm, Ab, Dskip, hinit, yg);
    k_xg<<<2048, 256, 0, stream>>>(yg, M2T, c2, xg);
    k_lstm<<<32, 512, 0, stream>>>(xg, w_hh, w_fc1, b_fc1, w_fc2, b_fc2, outp);
}

// Round 12
// 1580.173 us; speedup vs baseline: 1.1617x; 1.1617x over previous
//
#include <hip/hip_runtime.h>
#include <math.h>

#define Bsz 32
#define Lseq 1024
#define CHUNK 64
#define NCHUNK 16

__device__ __forceinline__ float fsig(float x) {
    return __builtin_amdgcn_rcpf(1.f + __expf(-x));
}
// Accurate fast tanh: Taylor for small |x| (avoids catastrophic cancellation
// in the exp form at x~1e-7, which killed R2), exp form for large |x|.
__device__ __forceinline__ float ftanh(float x) {
    float x2 = x * x;
    float poly = x * (1.f - 0.333333333f * x2 + 0.133333333f * x2 * x2);
    float big = 1.f - 2.f * __builtin_amdgcn_rcpf(1.f + __expf(2.f * x));
    return (x2 < 0.0025f) ? poly : big;
}
__device__ __forceinline__ float fsilu(float x) {
    return x * __builtin_amdgcn_rcpf(1.f + __expf(-x));
}

// ---------------- precompute: folded weight products ----------------
__global__ void k_pre(const float* w_proj, const float* b_proj, const float* w_inproj,
                      const float* A_log, const float* w_ih, const float* w_out,
                      const float* b_ih, const float* b_hh,
                      float* Ab, float* Minp, float* cinp, float* M2T, float* c2) {
    int idx = blockIdx.x * 256 + threadIdx.x;
    if (idx < 4096) {
        Ab[idx] = -expf(A_log[idx]);
    } else if (idx < 4096 + 6144) {
        int j = idx - 4096; int o = j / 12; int i = j - o * 12;
        float s = 0.f;
        for (int k = 0; k < 128; ++k) s += w_inproj[o*128+k] * w_proj[k*12+i];
        Minp[j] = s;
    } else if (idx < 4096 + 6144 + 512) {
        int o = idx - (4096 + 6144);
        float s = 0.f;
        for (int k = 0; k < 128; ++k) s += w_inproj[o*128+k] * b_proj[k];
        cinp[o] = s;
    } else if (idx < 4096 + 6144 + 512 + 131072) {
        int j = idx - (4096 + 6144 + 512);
        int o = j >> 8; int dd = j & 255;
        float s = 0.f;
        for (int k = 0; k < 128; ++k) s += w_ih[o*128+k] * w_out[k*256+dd];
        M2T[dd*512 + o] = s;    // transposed store
    } else if (idx < 4096 + 6144 + 512 + 131072 + 512) {
        int o = idx - (4096 + 6144 + 512 + 131072);
        c2[o] = b_ih[o] + b_hh[o];
    }
}

// ---------------- k_front: fused inproj + depthwise conv + SiLU ----------------
__global__ void __launch_bounds__(256) k_front(const float* __restrict__ x,
                       const float* __restrict__ Minp, const float* __restrict__ cinp,
                       const float* __restrict__ conv_w, const float* __restrict__ conv_b,
                       float* __restrict__ uc, float* __restrict__ zb) {
    __shared__ float xs[67*12];
    int b = blockIdx.x >> 4;
    int c = blockIdx.x & 15;
    int d = threadIdx.x;
    int t0 = c * 64;
    for (int i = d; i < 67*12; i += 256) {
        int trel = i / 12;
        int t = t0 - 3 + trel;
        xs[i] = (t >= 0) ? x[(b*1024 + t)*12 + (i - trel*12)] : 0.f;
    }
    __syncthreads();
    float mu[12], mz[12];
#pragma unroll
    for (int i = 0; i < 12; ++i) { mu[i] = Minp[d*12 + i]; mz[i] = Minp[(256+d)*12 + i]; }
    float cu = cinp[d], cz = cinp[256 + d];
    float cw0 = conv_w[d*4+0], cw1 = conv_w[d*4+1], cw2 = conv_w[d*4+2], cw3 = conv_w[d*4+3];
    float cb = conv_b[d];
    float r0 = 0.f, r1 = 0.f, r2 = 0.f;
#pragma unroll
    for (int k = 0; k < 3; ++k) {
        int t = t0 - 3 + k;
        float v = 0.f;
        if (t >= 0) {
            const float* xr = &xs[k*12];
            v = cu;
#pragma unroll
            for (int i = 0; i < 12; ++i) v += mu[i]*xr[i];
        }
        r0 = r1; r1 = r2; r2 = v;
    }
    for (int t = t0; t < t0 + 64; ++t) {
        const float* xr = &xs[(t - t0 + 3)*12];
        float u = cu, z = cz;
#pragma unroll
        for (int i = 0; i < 12; ++i) { u += mu[i]*xr[i]; z += mz[i]*xr[i]; }
        float cv = cb + cw0*r0 + cw1*r1 + cw2*r2 + cw3*u;
        uc[(b*1024 + t)*256 + d] = fsilu(cv);
        zb[(b*1024 + t)*256 + d] = z;
        r0 = r1; r1 = r2; r2 = u;
    }
}

// ---------------- k3: xdbc = uc @ w_xproj^T; dt = softplus(...) ----------------
__global__ void __launch_bounds__(256) k_xproj(const float* __restrict__ uc,
                        const float* __restrict__ w_xproj, const float* __restrict__ w_dt,
                        const float* __restrict__ b_dt,
                        float* __restrict__ dtb, float* __restrict__ Bm, float* __restrict__ Cm) {
    __shared__ float ur[256];
    __shared__ float xd[40];
    int tok = blockIdx.x;
    int tid = threadIdx.x;
    ur[tid] = uc[tok*256 + tid];
    __syncthreads();
    int j = tid >> 2, q = tid & 3;
    float s = 0.f;
    if (j < 40) {
        const float* wr = w_xproj + j*256 + q*64;
        const float* uq = ur + q*64;
#pragma unroll 8
        for (int k = 0; k < 64; ++k) s += wr[k] * uq[k];
    }
    s += __shfl_xor(s, 1);
    s += __shfl_xor(s, 2);
    if (j < 40 && q == 0) {
        xd[j] = s;
        if (j >= 8 && j < 24)      Bm[tok*16 + (j - 8)]  = s;
        else if (j >= 24)          Cm[tok*16 + (j - 24)] = s;
    }
    __syncthreads();
    float r = b_dt[tid];
    const float* wd = w_dt + tid*8;
#pragma unroll
    for (int jj = 0; jj < 8; ++jj) r += wd[jj] * xd[jj];
    r = (r > 20.f) ? r : log1pf(expf(r));   // softplus
    dtb[tok*256 + tid] = r;
}

// ---------------- SSM chunked scan ----------------
__global__ void __launch_bounds__(256) k_ssm_p1(const float* __restrict__ dtb,
                        const float* __restrict__ uc, const float* __restrict__ Bm,
                        const float* __restrict__ Ab,
                        float* __restrict__ h0end, float* __restrict__ Ssum) {
    __shared__ float Bs[CHUNK*16];
    int b = blockIdx.x >> 4;
    int c = blockIdx.x & 15;
    int d = threadIdx.x;
    int t0 = c * CHUNK;
    {
        const float* src = Bm + (b*1024 + t0) * 16;
        for (int i = d; i < CHUNK*16; i += 256) Bs[i] = src[i];
    }
    __syncthreads();
    float a[16], h[16];
#pragma unroll
    for (int s = 0; s < 16; ++s) { a[s] = Ab[d*16+s]; h[s] = 0.f; }
    float S = 0.f;
    const float* dtp = dtb + (b*1024 + t0)*256 + d;
    const float* up  = uc  + (b*1024 + t0)*256 + d;
    float dtv = dtp[0], uv = up[0];
    for (int t = 0; t < CHUNK; ++t) {
        float dtn = 0.f, un = 0.f;
        if (t < CHUNK-1) { dtn = dtp[(t+1)*256]; un = up[(t+1)*256]; }
        float dtu = dtv * uv;
        S += dtv;
#pragma unroll
        for (int s = 0; s < 16; ++s) {
            float dA = __expf(dtv * a[s]);
            h[s] = h[s]*dA + dtu * Bs[t*16+s];
        }
        dtv = dtn; uv = un;
    }
    float* he = h0end + ((b*256 + d)*16 + c)*16;
#pragma unroll
    for (int s = 0; s < 16; ++s) he[s] = h[s];
    Ssum[(b*256 + d)*16 + c] = S;
}

__global__ void k_ssm_p2(const float* __restrict__ h0end, const float* __restrict__ Ssum,
                         const float* __restrict__ Ab, float* __restrict__ hinit) {
    int gid = blockIdx.x * 256 + threadIdx.x;   // 131072 = 32*256*16
    int s = gid & 15;
    int bd = gid >> 4;
    int d = bd & 255;
    float a = Ab[d*16 + s];
    float carry = 0.f;
    const float* he = h0end + bd * 256;
    float* hi = hinit + bd * 256;
    const float* Sp = Ssum + bd * 16;
    for (int c = 0; c < 16; ++c) {
        hi[c*16 + s] = carry;
        carry = he[c*16 + s] + __expf(a * Sp[c]) * carry;
    }
}

__global__ void __launch_bounds__(256) k_ssm_p3(const float* __restrict__ dtb,
                        const float* __restrict__ uc, const float* __restrict__ zb,
                        const float* __restrict__ Bm, const float* __restrict__ Cm,
                        const float* __restrict__ Ab, const float* __restrict__ Dskip,
                        const float* __restrict__ hinit, float* __restrict__ yg) {
    __shared__ float Bs[CHUNK*16];
    __shared__ float Cs[CHUNK*16];
    int b = blockIdx.x >> 4;
    int c = blockIdx.x & 15;
    int d = threadIdx.x;
    int t0 = c * CHUNK;
    {
        const float* srcB = Bm + (b*1024 + t0) * 16;
        const float* srcC = Cm + (b*1024 + t0) * 16;
        for (int i = d; i < CHUNK*16; i += 256) { Bs[i] = srcB[i]; Cs[i] = srcC[i]; }
    }
    __syncthreads();
    float a[16], h[16];
    const float* hi = hinit + ((b*256 + d)*16 + c)*16;
#pragma unroll
    for (int s = 0; s < 16; ++s) { a[s] = Ab[d*16+s]; h[s] = hi[s]; }
    float Dv = Dskip[d];
    const float* dtp = dtb + (b*1024 + t0)*256 + d;
    const float* up  = uc  + (b*1024 + t0)*256 + d;
    const float* zp  = zb  + (b*1024 + t0)*256 + d;
    float* yp = yg + (b*1024 + t0)*256 + d;
    float dtv = dtp[0], uv = up[0], zv = zp[0];
    for (int t = 0; t < CHUNK; ++t) {
        float dtn = 0.f, un = 0.f, zn = 0.f;
        if (t < CHUNK-1) { dtn = dtp[(t+1)*256]; un = up[(t+1)*256]; zn = zp[(t+1)*256]; }
        float dtu = dtv * uv;
        float y = 0.f;
#pragma unroll
        for (int s = 0; s < 16; ++s) {
            float dA = __expf(dtv * a[s]);
            h[s] = h[s]*dA + dtu * Bs[t*16+s];
            y += h[s] * Cs[t*16+s];
        }
        yp[t*256] = (y + uv * Dv) * fsilu(zv);
        dtv = dtn; uv = un; zv = zn;
    }
}

// ---------------- k5: xg = yg @ M2^T + c2  via transposed M2T, coalesced ----
__global__ void __launch_bounds__(256) k_xg(const float* __restrict__ yg,
                      const float* __restrict__ M2T, const float* __restrict__ c2,
                      float* __restrict__ xg) {
    __shared__ float ytile[16][257];
    int tokbase = blockIdx.x * 16;
    int tid = threadIdx.x;
    for (int r = 0; r < 16; ++r) ytile[r][tid] = yg[(tokbase + r)*256 + tid];
    __syncthreads();
    int o0 = tid, o1 = tid + 256;
    float acc0[16], acc1[16];
    float cc0 = c2[o0], cc1 = c2[o1];
#pragma unroll
    for (int r = 0; r < 16; ++r) { acc0[r] = cc0; acc1[r] = cc1; }
#pragma unroll 4
    for (int k = 0; k < 256; ++k) {
        float m0 = M2T[k*512 + o0];
        float m1 = M2T[k*512 + o1];
#pragma unroll
        for (int r = 0; r < 16; ++r) {
            float yv = ytile[r][k];
            acc0[r] = fmaf(yv, m0, acc0[r]);
            acc1[r] = fmaf(yv, m1, acc1[r]);
        }
    }
    for (int r = 0; r < 16; ++r) {
        xg[(tokbase + r)*512 + o0] = acc0[r];
        xg[(tokbase + r)*512 + o1] = acc1[r];
    }
}

// ---------------- k6: LSTM (one block per batch) + FC head ----------------
// The R1-R11 invariant decoded: every variant issues ONE global gx load per
// step, and hipcc emits `s_waitcnt vmcnt(0)` before every s_barrier -> each
// of 1024 steps serially exposes L2/L3/HBM latency (~500-900 cyc). No MAC/LDS
// change could beat that wall (R9/R10/R11 nulls). Fix combo:
//  (1) 8-step register prefetch window: 8 gx loads issued once per window,
//      drained at the first step's barrier where ~800 cyc of MAC issue hides
//      them. Static indexing (rule #20) -> 8 explicitly unrolled STEPs.
//  (2) quad-gate layout (R10-proven): row = p*128+j, gates gathered with
//      __shfl(g,{1,2,3},4), computed on p==0 lanes of ALL 8 waves, ONE
//      barrier/step, double-buffered fp32 h (no gbuf round trip).
//  (3) weights: R9-proven 64-VGPR (named float4) + 64-AGPR residency.
#define LW(i) float4 W##i = wr[i];
#define DOTV(i, acc) { float4 hv = h4[i]; \
    acc = fmaf(hv.x, W##i.x, acc); acc = fmaf(hv.y, W##i.y, acc); \
    acc = fmaf(hv.z, W##i.z, acc); acc = fmaf(hv.w, W##i.w, acc); }
#define WADECL(i) float wa_##i##_0, wa_##i##_1, wa_##i##_2, wa_##i##_3;
#define WALOAD(i) { float4 v = wr[i]; \
    asm volatile("v_accvgpr_write_b32 %0, %1" : "=a"(wa_##i##_0) : "v"(v.x)); \
    asm volatile("v_accvgpr_write_b32 %0, %1" : "=a"(wa_##i##_1) : "v"(v.y)); \
    asm volatile("v_accvgpr_write_b32 %0, %1" : "=a"(wa_##i##_2) : "v"(v.z)); \
    asm volatile("v_accvgpr_write_b32 %0, %1" : "=a"(wa_##i##_3) : "v"(v.w)); }
#define DOTA(i, acc) { float4 hv = h4[i]; float t0, t1, t2, t3; \
    asm volatile("v_accvgpr_read_b32 %0, %1" : "=v"(t0) : "a"(wa_##i##_0)); \
    asm volatile("v_accvgpr_read_b32 %0, %1" : "=v"(t1) : "a"(wa_##i##_1)); \
    asm volatile("v_accvgpr_read_b32 %0, %1" : "=v"(t2) : "a"(wa_##i##_2)); \
    asm volatile("v_accvgpr_read_b32 %0, %1" : "=v"(t3) : "a"(wa_##i##_3)); \
    acc = fmaf(hv.x, t0, acc); acc = fmaf(hv.y, t1, acc); \
    acc = fmaf(hv.z, t2, acc); acc = fmaf(hv.w, t3, acc); }
#define STEP(gxv, par) { \
    const float4* h4 = (const float4*)hb[par]; \
    float a0 = 0.f, a1 = 0.f, a2 = 0.f, a3 = 0.f; \
    DOTV(0,  a0) DOTV(1,  a1) DOTV(2,  a2) DOTV(3,  a3) \
    DOTV(4,  a0) DOTV(5,  a1) DOTV(6,  a2) DOTV(7,  a3) \
    DOTV(8,  a0) DOTV(9,  a1) DOTV(10, a2) DOTV(11, a3) \
    DOTV(12, a0) DOTV(13, a1) DOTV(14, a2) DOTV(15, a3) \
    DOTA(16, a0) DOTA(17, a1) DOTA(18, a2) DOTA(19, a3) \
    DOTA(20, a0) DOTA(21, a1) DOTA(22, a2) DOTA(23, a3) \
    DOTA(24, a0) DOTA(25, a1) DOTA(26, a2) DOTA(27, a3) \
    DOTA(28, a0) DOTA(29, a1) DOTA(30, a2) DOTA(31, a3) \
    float g = (gxv) + ((a0 + a1) + (a2 + a3)); \
    float gf = __shfl(g, 1, 4); \
    float gc = __shfl(g, 2, 4); \
    float go = __shfl(g, 3, 4); \
    if (p == 0) { \
        float ig = fsig(g); \
        float fg = fsig(gf); \
        float gg = ftanh(gc); \
        float og = fsig(go); \
        cstate = fg*cstate + ig*gg; \
        hb[(par)^1][j] = og * ftanh(cstate); \
    } \
    __syncthreads(); \
}

__global__ void __launch_bounds__(512)
k_lstm(const float* __restrict__ xg,
                       const float* __restrict__ w_hh,
                       const float* __restrict__ w_fc1, const float* __restrict__ b_fc1,
                       const float* __restrict__ w_fc2, const float* __restrict__ b_fc2,
                       float* __restrict__ out) {
    __shared__ float hb[2][128];
    __shared__ float fcbuf[128];
    int b = blockIdx.x;
    int tid = threadIdx.x;
    int p = tid & 3;           // gate index (i,f,g,o)
    int j = tid >> 2;          // hidden unit
    int row = p * 128 + j;     // w_hh / xg row this thread owns
    const float4* wr = (const float4*)(w_hh + row*128);
    // k = 0..63 in named VGPR float4s
    LW(0)  LW(1)  LW(2)  LW(3)  LW(4)  LW(5)  LW(6)  LW(7)
    LW(8)  LW(9)  LW(10) LW(11) LW(12) LW(13) LW(14) LW(15)
    // k = 64..127 in AGPRs
    WADECL(16) WADECL(17) WADECL(18) WADECL(19)
    WADECL(20) WADECL(21) WADECL(22) WADECL(23)
    WADECL(24) WADECL(25) WADECL(26) WADECL(27)
    WADECL(28) WADECL(29) WADECL(30) WADECL(31)
    WALOAD(16) WALOAD(17) WALOAD(18) WALOAD(19)
    WALOAD(20) WALOAD(21) WALOAD(22) WALOAD(23)
    WALOAD(24) WALOAD(25) WALOAD(26) WALOAD(27)
    WALOAD(28) WALOAD(29) WALOAD(30) WALOAD(31)
    float cstate = 0.f;
    if (tid < 128) hb[0][tid] = 0.f;
    __syncthreads();
    const float* xp = xg + (size_t)b * 1024 * 512 + row;
    // preload window 0 (steps 0..7)
    float n0 = xp[0*512], n1 = xp[1*512], n2 = xp[2*512], n3 = xp[3*512];
    float n4 = xp[4*512], n5 = xp[5*512], n6 = xp[6*512], n7 = xp[7*512];
    for (int tw = 0; tw < 1024; tw += 8) {
        float g0=n0, g1=n1, g2=n2, g3=n3, g4=n4, g5=n5, g6=n6, g7=n7;
        if (tw + 8 < 1024) {
            const float* q = xp + (size_t)(tw + 8) * 512;
            n0 = q[0*512]; n1 = q[1*512]; n2 = q[2*512]; n3 = q[3*512];
            n4 = q[4*512]; n5 = q[5*512]; n6 = q[6*512]; n7 = q[7*512];
        }
        STEP(g0, 0) STEP(g1, 1) STEP(g2, 0) STEP(g3, 1)
        STEP(g4, 0) STEP(g5, 1) STEP(g6, 0) STEP(g7, 1)
    }
    // final h: step t=1023 (par 1) wrote hb[0]
    if (tid < 128) {
        float s = b_fc1[tid];
        const float* wf = w_fc1 + tid*128;
#pragma unroll 4
        for (int k = 0; k < 128; ++k) s += wf[k] * hb[0][k];
        fcbuf[tid] = fmaxf(s, 0.f);
    }
    __syncthreads();
    if (tid < 5) {
        float s = b_fc2[tid];
        const float* wf = w_fc2 + tid*128;
        for (int k = 0; k < 128; ++k) s += wf[k] * fcbuf[k];
        out[b*5 + tid] = s;
    }
}

// ---------------- launch ----------------
extern "C" void kernel_launch(void* const* d_in, const int* in_sizes, int n_in,
                              void* d_out, int out_size, void* d_ws, size_t ws_size,
                              hipStream_t stream) {
    const float* x        = (const float*)d_in[0];
    const float* w_proj   = (const float*)d_in[1];
    const float* b_proj   = (const float*)d_in[2];
    const float* w_inproj = (const float*)d_in[3];
    const float* conv_w   = (const float*)d_in[4];
    const float* conv_b   = (const float*)d_in[5];
    const float* w_xproj  = (const float*)d_in[6];
    const float* w_dt     = (const float*)d_in[7];
    const float* b_dt     = (const float*)d_in[8];
    const float* A_log    = (const float*)d_in[9];
    const float* Dskip    = (const float*)d_in[10];
    const float* w_out    = (const float*)d_in[11];
    const float* w_ih     = (const float*)d_in[12];
    const float* w_hh     = (const float*)d_in[13];
    const float* b_ih     = (const float*)d_in[14];
    const float* b_hh     = (const float*)d_in[15];
    const float* w_fc1    = (const float*)d_in[16];
    const float* b_fc1    = (const float*)d_in[17];
    const float* w_fc2    = (const float*)d_in[18];
    const float* b_fc2    = (const float*)d_in[19];
    float* outp = (float*)d_out;

    float* ws = (float*)d_ws;
    size_t off = 0;
    float* uc   = ws + off; off += 8388608;   // xg aliases uc+zb after p3
    float* zb   = ws + off; off += 8388608;
    float* dtb  = ws + off; off += 8388608;
    float* yg   = ws + off; off += 8388608;
    float* Bm   = ws + off; off += 524288;
    float* Cm   = ws + off; off += 524288;
    float* Ab   = ws + off; off += 4096;
    float* Minp = ws + off; off += 6144;
    float* cinp = ws + off; off += 512;
    float* M2T  = ws + off; off += 131072;
    float* c2   = ws + off; off += 512;
    float* h0end = ws + off; off += 2097152;
    float* Ssum  = ws + off; off += 131072;
    float* hinit = ws + off; off += 2097152;
    float* xg = uc;    // alias: spans uc+zb (16.7M floats), both dead after ssm_p3

    k_pre<<<556, 256, 0, stream>>>(w_proj, b_proj, w_inproj, A_log, w_ih, w_out,
                                   b_ih, b_hh, Ab, Minp, cinp, M2T, c2);
    k_front<<<512, 256, 0, stream>>>(x, Minp, cinp, conv_w, conv_b, uc, zb);
    k_xproj<<<32768, 256, 0, stream>>>(uc, w_xproj, w_dt, b_dt, dtb, Bm, Cm);
    k_ssm_p1<<<512, 256, 0, stream>>>(dtb, uc, Bm, Ab, h0end, Ssum);
    k_ssm_p2<<<512, 256, 0, stream>>>(h0end, Ssum, Ab, hinit);
    k_ssm_p3<<<512, 256, 0, stream>>>(dtb, uc, zb, Bm, Cm, Ab, Dskip, hinit, yg);
    k_xg<<<2048, 256, 0, stream>>>(yg, M2T, c2, xg);
    k_lstm<<<32, 512, 0, stream>>>(xg, w_hh, w_fc1, b_fc1, w_fc2, b_fc2, outp);
}